// Round 6
// baseline (211.138 us; speedup 1.0000x reference)
//
#include <hip/hip_runtime.h>
#include <hip/hip_bf16.h>

// ---------------- problem constants ----------------
#define NSEQ 2048
#define HIDDIM 1024
#define NH 16
#define DHEAD 64
#define NW 129      // 2*WK+1
#define AKS 132     // padded a_k row stride (floats)
#define VTS 132     // Vts LDS row stride (f16): reads conflict-free, 8B aligned

typedef float          f32x4 __attribute__((ext_vector_type(4)));
typedef _Float16       f16x4 __attribute__((ext_vector_type(4)));
typedef _Float16       f16x8 __attribute__((ext_vector_type(8)));
typedef unsigned short u16x8 __attribute__((ext_vector_type(8)));
typedef unsigned short u16;

__device__ __forceinline__ float b2f(u16 u){ return __uint_as_float(((unsigned)u) << 16); }
// dtype-hedged scalar load: flag=1 -> bf16, flag=0 -> f32
__device__ __forceinline__ float ld_any(const void* p, long idx, int flag){
  return flag ? b2f(((const u16*)p)[idx]) : ((const float*)p)[idx];
}

// ---------------- workspace layout (all 16B aligned) ----------------
static const size_t OFF_Q    = 0;                        // f16 [H][N][DH]      4 MiB
static const size_t OFF_K    = (size_t)4  << 20;         // f16 [H][N][DH]      4 MiB
static const size_t OFF_VT   = (size_t)8  << 20;         // f16 [H][DH][N]      4 MiB
static const size_t OFF_WT   = (size_t)12 << 20;         // f16 [3][1024][1024] 6 MiB (transposed [o][k])
static const size_t OFF_AK   = (size_t)18 << 20;         // f32 [H][N][AKS]; ak bias -> band logits
static const size_t OFF_M    = OFF_AK + (size_t)NH * NSEQ * AKS * 4;   // f32 [2][H][N]
static const size_t OFF_L    = OFF_M + (size_t)2 * NH * NSEQ * 4;      // f32 [2][H][N]
static const size_t OFF_CTXP = OFF_L + (size_t)2 * NH * NSEQ * 4;      // f32 [2][N][HID] 16 MiB
static const size_t OFF_HSF  = OFF_CTXP + (size_t)2 * NSEQ * HIDDIM * 4; // f16 [N][HID] 4 MiB
static const size_t OFF_BIAS = OFF_HSF + (size_t)NSEQ * HIDDIM * 2;    // f32 [3][1024]
static const size_t OFF_WRK  = OFF_BIAS + 3 * 1024 * 4;                // f32 [64][129]
static const size_t OFF_WRV  = OFF_WRK + (size_t)DHEAD * NW * 4;       // f32 [129][64]
static const size_t OFF_EXT  = OFF_WRV + (size_t)NW * DHEAD * 4;       // f32 [N]

// ---------------- prep: dtype-detect + hs->f16 + W transpose + small tensors ----------------
// blocks [0,1024): hs cvt; [1024,1792): W transpose; [1792,1877): small tensors.
__global__ void prep_kernel(const void* __restrict__ hs,
                            const void* __restrict__ Wq, const void* __restrict__ Wk,
                            const void* __restrict__ Wv,
                            const void* __restrict__ bq, const void* __restrict__ bk,
                            const void* __restrict__ bv, const void* __restrict__ wrk,
                            const void* __restrict__ wrv, const void* __restrict__ mask,
                            _Float16* __restrict__ hsf, _Float16* __restrict__ Wt,
                            float* __restrict__ biasf, float* __restrict__ wrkf,
                            float* __restrict__ wrvf, float* __restrict__ extf){
  __shared__ __attribute__((aligned(16))) _Float16 tile[64][65];
  const int flag = (((const unsigned*)mask)[0] == 0x3F800000u) ? 0 : 1;
  const int b = blockIdx.x, t = threadIdx.x;
  if (b < 1024){
    const long base = (long)(b * 256 + t) * 8;
    f16x8 o;
    if (flag){
      const u16* src = (const u16*)hs;
#pragma unroll
      for (int e = 0; e < 8; e++) o[e] = (_Float16)b2f(src[base + e]);
    } else {
      const float* src = (const float*)hs;
#pragma unroll
      for (int e = 0; e < 8; e++) o[e] = (_Float16)src[base + e];
    }
    *(f16x8*)(hsf + base) = o;
  } else if (b < 1792){
    const int b2 = b - 1024;
    const int z = b2 >> 8, r = b2 & 255;
    const int o0 = (r & 15) * 64, k0 = (r >> 4) * 64;
    const void* src = (z == 0) ? Wq : ((z == 1) ? Wk : Wv);
    _Float16* dst = Wt + (size_t)z * 1024 * 1024;
#pragma unroll
    for (int c = 0; c < 2; c++){
      int idx = t + 256 * c;
      int rr = idx >> 3, c8 = (idx & 7) * 8;
      long off = (long)(k0 + rr) * 1024 + o0 + c8;
#pragma unroll
      for (int e = 0; e < 8; e++) tile[rr][c8 + e] = (_Float16)ld_any(src, off + e, flag);
    }
    __syncthreads();
#pragma unroll
    for (int c = 0; c < 2; c++){
      int idx = t + 256 * c;
      int orow = idx >> 3, k8 = (idx & 7) * 8;
      f16x8 v;
#pragma unroll
      for (int e = 0; e < 8; e++) v[e] = tile[k8 + e][orow];
      *(f16x8*)(dst + (size_t)(o0 + orow) * 1024 + k0 + k8) = v;
    }
  } else {
    const int idx = (b - 1792) * 256 + t;
    if (idx < 1024)            biasf[idx] = ld_any(bq, idx, flag);
    else if (idx < 2048)       biasf[idx] = ld_any(bk, idx - 1024, flag);
    else if (idx < 3072)       biasf[idx] = ld_any(bv, idx - 2048, flag);
    else if (idx < 3072 + 8256)  wrkf[idx - 3072]  = ld_any(wrk, idx - 3072, flag);
    else if (idx < 3072 + 16512) wrvf[idx - 11328] = ld_any(wrv, idx - 11328, flag);
    else if (idx < 3072 + 16512 + 2048)
      extf[idx - 19584] = (1.f - ld_any(mask, idx - 19584, flag)) * -1.0e30f;
  }
}

// ---------------- QKV projection GEMM (f16 MFMA, reg-double-buffered staging) ----------------
__launch_bounds__(256, 2)
__global__ void qkv_kernel(const _Float16* __restrict__ hsf, const _Float16* __restrict__ Wt,
                           const float* __restrict__ biasf,
                           _Float16* __restrict__ Qf, _Float16* __restrict__ Kf,
                           _Float16* __restrict__ Vtf){
  __shared__ __attribute__((aligned(16))) _Float16 As[128 * 40];
  __shared__ __attribute__((aligned(16))) _Float16 Bs[128 * 40];
  const int z = blockIdx.z;
  const _Float16* Wz = Wt + (size_t)z * 1024 * 1024;
  const int o0 = blockIdx.x * 128, m0 = blockIdx.y * 128;
  const int t = threadIdx.x, lane = t & 63, wave = t >> 6;
  const int wm = wave >> 1, wn = wave & 1;
  const int q = lane >> 4, ln = lane & 15;
  const int srow = t >> 2, scol = (t & 3) * 8;       // staging coords (c adds 64 rows)
  f32x4 acc[4][4];
#pragma unroll
  for (int a = 0; a < 4; a++)
#pragma unroll
    for (int b = 0; b < 4; b++) acc[a][b] = (f32x4){0.f, 0.f, 0.f, 0.f};

  f16x8 ar[2], br[2];
#pragma unroll
  for (int c = 0; c < 2; c++){
    ar[c] = *(const f16x8*)(hsf + (size_t)(m0 + srow + 64 * c) * 1024 + scol);
    br[c] = *(const f16x8*)(Wz + (size_t)(o0 + srow + 64 * c) * 1024 + scol);
  }
  for (int k0 = 0; k0 < 1024; k0 += 32){
#pragma unroll
    for (int c = 0; c < 2; c++){
      *(f16x8*)&As[(srow + 64 * c) * 40 + scol] = ar[c];
      *(f16x8*)&Bs[(srow + 64 * c) * 40 + scol] = br[c];
    }
    __syncthreads();
    if (k0 + 32 < 1024){
#pragma unroll
      for (int c = 0; c < 2; c++){
        ar[c] = *(const f16x8*)(hsf + (size_t)(m0 + srow + 64 * c) * 1024 + k0 + 32 + scol);
        br[c] = *(const f16x8*)(Wz + (size_t)(o0 + srow + 64 * c) * 1024 + k0 + 32 + scol);
      }
    }
    f16x8 af[4], bf[4];
#pragma unroll
    for (int mt = 0; mt < 4; mt++) af[mt] = *(const f16x8*)&As[(wm * 64 + mt * 16 + ln) * 40 + q * 8];
#pragma unroll
    for (int nt = 0; nt < 4; nt++) bf[nt] = *(const f16x8*)&Bs[(wn * 64 + nt * 16 + ln) * 40 + q * 8];
#pragma unroll
    for (int mt = 0; mt < 4; mt++)
#pragma unroll
      for (int nt = 0; nt < 4; nt++)
        acc[mt][nt] = __builtin_amdgcn_mfma_f32_16x16x32_f16(af[mt], bf[nt], acc[mt][nt], 0, 0, 0);
    __syncthreads();
  }
#pragma unroll
  for (int nt = 0; nt < 4; nt++){
    int o = o0 + wn * 64 + nt * 16 + ln;
    float bval = biasf[z * 1024 + o];
    int hh = o >> 6, dd = o & 63;
#pragma unroll
    for (int mt = 0; mt < 4; mt++){
      int nb = m0 + wm * 64 + mt * 16 + q * 4;
      if (z == 2){
        f16x4 pk;
#pragma unroll
        for (int r = 0; r < 4; r++) pk[r] = (_Float16)(acc[mt][nt][r] + bval);
        *(f16x4*)(Vtf + (size_t)(hh * 64 + dd) * 2048 + nb) = pk;
      } else {
        _Float16* dstp = (z == 0) ? Qf : Kf;
#pragma unroll
        for (int r = 0; r < 4; r++)
          dstp[(size_t)(hh * 2048 + nb + r) * 64 + dd] = (_Float16)(acc[mt][nt][r] + bval);
      }
    }
  }
}

// ---------------- a_k[h][i][w] = Q[h][i][:] . W_rel_k[:][w] ----------------
__launch_bounds__(256, 2)
__global__ void ak_kernel(const _Float16* __restrict__ Qf, const float* __restrict__ wrkf,
                          float* __restrict__ ak){
  __shared__ __attribute__((aligned(16))) _Float16 WrkT[144 * 72]; // [w][d], zero-pad w>=129
  const int h = blockIdx.y;
  const int i0 = blockIdx.x * 128;
  const int t = threadIdx.x, lane = t & 63, wave = t >> 6;
  const int q = lane >> 4, ln = lane & 15;
  for (int c = 0; c < 36; c++){
    int idx = t + 256 * c;
    int w = idx >> 6, d = idx & 63;
    float v = (w < NW) ? wrkf[d * NW + w] : 0.f;
    WrkT[w * 72 + d] = (_Float16)v;
  }
  __syncthreads();
  f16x8 afr[2][2];
#pragma unroll
  for (int mt = 0; mt < 2; mt++){
    int row = i0 + wave * 32 + mt * 16 + ln;
#pragma unroll
    for (int ks = 0; ks < 2; ks++)
      afr[mt][ks] = *(const f16x8*)(Qf + (size_t)(h * 2048 + row) * 64 + ks * 32 + q * 8);
  }
  f32x4 acc[2][9];
#pragma unroll
  for (int a = 0; a < 2; a++)
#pragma unroll
    for (int b = 0; b < 9; b++) acc[a][b] = (f32x4){0.f, 0.f, 0.f, 0.f};
#pragma unroll
  for (int nt = 0; nt < 9; nt++){
    f16x8 bfr0 = *(const f16x8*)&WrkT[(nt * 16 + ln) * 72 + q * 8];
    f16x8 bfr1 = *(const f16x8*)&WrkT[(nt * 16 + ln) * 72 + 32 + q * 8];
#pragma unroll
    for (int mt = 0; mt < 2; mt++){
      acc[mt][nt] = __builtin_amdgcn_mfma_f32_16x16x32_f16(afr[mt][0], bfr0, acc[mt][nt], 0, 0, 0);
      acc[mt][nt] = __builtin_amdgcn_mfma_f32_16x16x32_f16(afr[mt][1], bfr1, acc[mt][nt], 0, 0, 0);
    }
  }
#pragma unroll
  for (int nt = 0; nt < 9; nt++){
    int w = nt * 16 + ln;
    if (w > 128) continue;
#pragma unroll
    for (int mt = 0; mt < 2; mt++){
      int ib = i0 + wave * 32 + mt * 16 + q * 4;
#pragma unroll
      for (int r = 0; r < 4; r++)
        ak[(size_t)(h * 2048 + ib + r) * AKS + w] = acc[mt][nt][r];
    }
  }
}

// ---------------- flash attention, K-split + reg double-buffer + ones-row l ----------------
// blockIdx: x=head, y=qtile(64 rows), z=jhalf. Unnormalized partial ctx + (m,l) per half.
// Vts has 16 extra static rows: row 64 = ones (l via MFMA), rows 65..79 = 0.
__launch_bounds__(256, 4)
__global__ void flash_kernel(const float* __restrict__ extf,
                             const _Float16* __restrict__ Qf, const _Float16* __restrict__ Kf,
                             const _Float16* __restrict__ Vtf, float* akm,
                             float* __restrict__ ctxpart, float* __restrict__ mws,
                             float* __restrict__ lws){
  __shared__ __attribute__((aligned(16))) _Float16 Ks[128 * 72];   // K tile [j][d]
  __shared__ __attribute__((aligned(16))) _Float16 Vts[80 * VTS];  // Vt tile [d][j] + ones rows
  __shared__ __attribute__((aligned(16))) float exts[128];
  const int h = blockIdx.x, qt = blockIdx.y, jh = blockIdx.z;
  const int t = threadIdx.x, lane = t & 63, wave = t >> 6;
  const int q = lane >> 4, ln = lane & 15;
  const int ibase = qt * 64 + wave * 16;
  const int i = ibase + ln;
  f16x8 qfrag[2];
  {
    const _Float16* qrow = Qf + (size_t)(h * 2048 + i) * 64;
    qfrag[0] = *(const f16x8*)(qrow + q * 8);
    qfrag[1] = *(const f16x8*)(qrow + 32 + q * 8);
  }
  // static ones/zero rows of Vts (never rewritten; visible after first barrier)
  for (int k = t; k < 16 * VTS; k += 256){
    int rr = k / VTS, cc = k - rr * VTS;
    Vts[(64 + rr) * VTS + cc] = (rr == 0 && cc < 128) ? (_Float16)1.f : (_Float16)0.f;
  }
  f32x4 accc[5];
#pragma unroll
  for (int dt = 0; dt < 5; dt++) accc[dt] = (f32x4){0.f, 0.f, 0.f, 0.f};
  float m_i = -1.0e30f;
  float* akrow = akm + (size_t)(h * 2048 + i) * AKS;
  const int jbase = jh * 1024;
  const int krow = t >> 3, kcol = (t & 7) * 8;     // K staging coords (c adds 32 rows)
  const int vrow = t >> 4, vcol = (t & 15) * 8;    // V staging coords (c adds 16 rows)

  f16x8 kr[4], vr[4]; float er = 0.f;
#pragma unroll
  for (int c = 0; c < 4; c++){
    kr[c] = *(const f16x8*)(Kf + (size_t)(h * 2048 + jbase + krow + 32 * c) * 64 + kcol);
    vr[c] = *(const f16x8*)(Vtf + (size_t)(h * 64 + vrow + 16 * c) * 2048 + jbase + vcol);
  }
  if (t < 128) er = extf[jbase + t];

  for (int jt = 0; jt < 8; jt++){
    const int j0 = jbase + jt * 128;
    // ---- commit staged regs to LDS ----
#pragma unroll
    for (int c = 0; c < 4; c++){
      *(f16x8*)&Ks[(krow + 32 * c) * 72 + kcol] = kr[c];
      // Vts rows are only 8B aligned (VTS=132): two f16x4 stores
      f16x4 lo = {vr[c][0], vr[c][1], vr[c][2], vr[c][3]};
      f16x4 hi = {vr[c][4], vr[c][5], vr[c][6], vr[c][7]};
      *(f16x4*)&Vts[(vrow + 16 * c) * VTS + vcol] = lo;
      *(f16x4*)&Vts[(vrow + 16 * c) * VTS + vcol + 4] = hi;
    }
    if (t < 128) exts[t] = er;
    __syncthreads();
    // ---- prefetch next tile (overlaps with compute below) ----
    if (jt < 7){
      const int j1 = j0 + 128;
#pragma unroll
      for (int c = 0; c < 4; c++){
        kr[c] = *(const f16x8*)(Kf + (size_t)(h * 2048 + j1 + krow + 32 * c) * 64 + kcol);
        vr[c] = *(const f16x8*)(Vtf + (size_t)(h * 64 + vrow + 16 * c) * 2048 + j1 + vcol);
      }
      if (t < 128) er = extf[j1 + t];
    }
    // ---- S^T = K . Q^T ----
    f32x4 s[8];
#pragma unroll
    for (int mt = 0; mt < 8; mt++){
      f16x8 kf0 = *(const f16x8*)&Ks[(mt * 16 + ln) * 72 + q * 8];
      f16x8 kf1 = *(const f16x8*)&Ks[(mt * 16 + ln) * 72 + 32 + q * 8];
      f32x4 zz = (f32x4){0.f, 0.f, 0.f, 0.f};
      zz = __builtin_amdgcn_mfma_f32_16x16x32_f16(kf0, qfrag[0], zz, 0, 0, 0);
      zz = __builtin_amdgcn_mfma_f32_16x16x32_f16(kf1, qfrag[1], zz, 0, 0, 0);
      s[mt] = zz;
    }
    // ---- banded key bias + scale + mask; write back final band logits ----
    const bool band = (j0 <= ibase + 79) && (j0 + 127 >= ibase - 64);
#pragma unroll
    for (int mt = 0; mt < 8; mt++){
      f32x4 ev = *(const f32x4*)&exts[mt * 16 + q * 4];
#pragma unroll
      for (int r = 0; r < 4; r++){
        float x = s[mt][r];
        int w = j0 + mt * 16 + q * 4 + r - i + 64;
        if (band && (unsigned)w <= 128u){
          x = (x + akrow[w]) * 0.125f + ev[r];
          akrow[w] = x;
        } else {
          x = x * 0.125f + ev[r];
        }
        s[mt][r] = x;
      }
    }
    // ---- online softmax (no explicit row-sum: l comes from ones-row MFMA) ----
    float tmax = -1.0e30f;
#pragma unroll
    for (int mt = 0; mt < 8; mt++)
#pragma unroll
      for (int r = 0; r < 4; r++) tmax = fmaxf(tmax, s[mt][r]);
    tmax = fmaxf(tmax, __shfl_xor(tmax, 16, 64));
    tmax = fmaxf(tmax, __shfl_xor(tmax, 32, 64));
    float mnew = fmaxf(m_i, tmax);
    float alpha = __expf(m_i - mnew);
    m_i = mnew;
#pragma unroll
    for (int dt = 0; dt < 5; dt++)
#pragma unroll
      for (int r = 0; r < 4; r++) accc[dt][r] *= alpha;
    f16x4 pf[8];
#pragma unroll
    for (int mt = 0; mt < 8; mt++)
#pragma unroll
      for (int r = 0; r < 4; r++)
        pf[mt][r] = (_Float16)__expf(s[mt][r] - mnew);
    // ---- PV (+ ones row -> l in accc[4]) ----
#pragma unroll
    for (int dt = 0; dt < 5; dt++){
#pragma unroll
      for (int ks = 0; ks < 8; ks++){
        f16x4 vf = *(const f16x4*)&Vts[(dt * 16 + ln) * VTS + ks * 16 + q * 4];
        accc[dt] = __builtin_amdgcn_mfma_f32_16x16x16f16(vf, pf[ks], accc[dt], 0, 0, 0);
      }
    }
    __syncthreads();
  }
  // ---- epilogue: unnormalized partial ctx; l sits in accc[4][0] on quad 0 ----
  float* cdst = ctxpart + (size_t)jh * NSEQ * HIDDIM;
#pragma unroll
  for (int dt = 0; dt < 4; dt++)
    *(f32x4*)(cdst + (size_t)i * 1024 + h * 64 + dt * 16 + q * 4) = accc[dt];
  if (q == 0){
    mws[jh * NH * NSEQ + h * 2048 + i] = m_i;
    lws[jh * NH * NSEQ + h * 2048 + i] = accc[4][0];
  }
}

// ---------------- finish: merge partials + band correction via MFMA ----------------
__launch_bounds__(256, 2)
__global__ void finish_kernel(const float* __restrict__ sband, const float* __restrict__ mws,
                              const float* __restrict__ lws, const float* __restrict__ wrvf,
                              const float* __restrict__ ctxpart, float* __restrict__ out){
  __shared__ __attribute__((aligned(16))) _Float16 WrvT[64 * 144];  // [d][w], zero-pad w>=129
  __shared__ __attribute__((aligned(16))) _Float16 pT[144 * 72];    // [w][i_local]
  __shared__ __attribute__((aligned(16))) float sM[64], sIL[64], sC0[64], sC1[64];
  const int qt = blockIdx.x, h = blockIdx.y;
  const int i0 = qt * 64;
  const int t = threadIdx.x, lane = t & 63, wave = t >> 6;
  const int q = lane >> 4, ln = lane & 15;
  for (int c = 0; c < 36; c++){
    int idx = c * 256 + t;
    int w = idx >> 6, d = idx & 63;
    WrvT[d * 144 + w] = (w < NW) ? (_Float16)wrvf[w * 64 + d] : (_Float16)0.f;
  }
  if (t < 64){
    int i = i0 + t;
    float m0 = mws[h * 2048 + i],            m1 = mws[NH * NSEQ + h * 2048 + i];
    float l0 = lws[h * 2048 + i],            l1 = lws[NH * NSEQ + h * 2048 + i];
    float M = fmaxf(m0, m1);
    float a0 = __expf(m0 - M), a1 = __expf(m1 - M);
    float L = a0 * l0 + a1 * l1;
    float iL = 1.f / L;
    sM[t] = M; sIL[t] = iL; sC0[t] = a0 * iL; sC1[t] = a1 * iL;
  }
  __syncthreads();
  for (int ii = 0; ii < 16; ii++){
    int il = wave * 16 + ii;
    float Mv = sM[il], ILv = sIL[il];
    const float* srow = sband + (size_t)(h * 2048 + i0 + il) * AKS;
#pragma unroll
    for (int c = 0; c < 3; c++){
      int w = lane + 64 * c;
      if (w < 144){
        float p = (w < NW) ? __expf(srow[w] - Mv) * ILv : 0.f;
        pT[w * 72 + il] = (_Float16)p;
      }
    }
  }
  __syncthreads();
  f32x4 acc[4];
#pragma unroll
  for (int mt = 0; mt < 4; mt++) acc[mt] = (f32x4){0.f, 0.f, 0.f, 0.f};
#pragma unroll
  for (int ks = 0; ks < 9; ks++){
    f16x4 bfr;
#pragma unroll
    for (int j = 0; j < 4; j++) bfr[j] = pT[(ks * 16 + q * 4 + j) * 72 + wave * 16 + ln];
#pragma unroll
    for (int mt = 0; mt < 4; mt++){
      f16x4 afr = *(const f16x4*)&WrvT[(mt * 16 + ln) * 144 + ks * 16 + q * 4];
      acc[mt] = __builtin_amdgcn_mfma_f32_16x16x16f16(afr, bfr, acc[mt], 0, 0, 0);
    }
  }
  const int i = i0 + wave * 16 + ln;
  const float c0 = sC0[wave * 16 + ln], c1 = sC1[wave * 16 + ln];
  const float* p0 = ctxpart;
  const float* p1 = ctxpart + (size_t)NSEQ * HIDDIM;
#pragma unroll
  for (int mt = 0; mt < 4; mt++){
    size_t off = (size_t)i * 1024 + h * 64 + mt * 16 + q * 4;
    f32x4 A0 = *(const f32x4*)(p0 + off);
    f32x4 A1 = *(const f32x4*)(p1 + off);
    f32x4 o4;
#pragma unroll
    for (int r = 0; r < 4; r++) o4[r] = c0 * A0[r] + c1 * A1[r] + acc[mt][r];
    *(f32x4*)(out + off) = o4;
  }
}

// ---------------- launcher ----------------
extern "C" void kernel_launch(void* const* d_in, const int* in_sizes, int n_in,
                              void* d_out, int out_size, void* d_ws, size_t ws_size,
                              hipStream_t stream){
  const void* hs   = d_in[0];
  const void* mask = d_in[1];
  const void* Wq   = d_in[2];
  const void* bq   = d_in[3];
  const void* Wk   = d_in[4];
  const void* bk   = d_in[5];
  const void* Wv   = d_in[6];
  const void* bv   = d_in[7];
  const void* Wrk  = d_in[8];
  const void* Wrv  = d_in[9];
  float* out = (float*)d_out;

  char* ws = (char*)d_ws;
  _Float16* Qf    = (_Float16*)(ws + OFF_Q);
  _Float16* Kf    = (_Float16*)(ws + OFF_K);
  _Float16* Vtf   = (_Float16*)(ws + OFF_VT);
  _Float16* Wt    = (_Float16*)(ws + OFF_WT);
  float*    akp   = (float*)   (ws + OFF_AK);
  float*    mp    = (float*)   (ws + OFF_M);
  float*    lp    = (float*)   (ws + OFF_L);
  float*    ctxp  = (float*)   (ws + OFF_CTXP);
  _Float16* hsf   = (_Float16*)(ws + OFF_HSF);
  float*    biasf = (float*)   (ws + OFF_BIAS);
  float*    wrkf  = (float*)   (ws + OFF_WRK);
  float*    wrvf  = (float*)   (ws + OFF_WRV);
  float*    extf  = (float*)   (ws + OFF_EXT);

  prep_kernel  <<<dim3(1877),      256, 0, stream>>>(hs, Wq, Wk, Wv, bq, bk, bv, Wrk, Wrv, mask,
                                                     hsf, Wt, biasf, wrkf, wrvf, extf);
  qkv_kernel   <<<dim3(8, 16, 3),  256, 0, stream>>>(hsf, Wt, biasf, Qf, Kf, Vtf);
  ak_kernel    <<<dim3(16, 16),    256, 0, stream>>>(Qf, wrkf, akp);
  flash_kernel <<<dim3(16, 32, 2), 256, 0, stream>>>(extf, Qf, Kf, Vtf, akp, ctxp, mp, lp);
  finish_kernel<<<dim3(32, 16),    256, 0, stream>>>(akp, mp, lp, wrvf, ctxp, out);
}